// Round 1
// baseline (1426.585 us; speedup 1.0000x reference)
//
#include <hip/hip_runtime.h>

// GCN encoder: h = relu(gcn(x,W1,b1)); mu = gcn(h,Wmu,bmu); ls = gcn(h,Wls,bls)
// gcn(x,W,b) = scatter_add(norm * (xW)[src] -> dst) + (xW)*dinv^2 + b
// dinv = rsqrt(deg+1), deg = in-degree from dst.

static constexpr int FEAT = 64;

__global__ void deg_count_kernel(const int* __restrict__ dst, float* __restrict__ deg, int E) {
    int e = blockIdx.x * blockDim.x + threadIdx.x;
    if (e < E) atomicAdd(&deg[dst[e]], 1.0f);
}

__global__ void dinv_kernel(float* __restrict__ deg, int n) {
    int i = blockIdx.x * blockDim.x + threadIdx.x;
    if (i < n) deg[i] = rsqrtf(deg[i] + 1.0f);
}

// C[n][64] = X[n][K] @ W[K][64]; block = 256 threads = 4 rows x 64 cols.
template<int K>
__global__ void gemm_kernel(const float* __restrict__ X, const float* __restrict__ W,
                            float* __restrict__ C, int n) {
    __shared__ float Ws[K * FEAT];
    for (int i = threadIdx.x; i < K * FEAT; i += 256) Ws[i] = W[i];
    __syncthreads();
    int col = threadIdx.x & 63;
    int row = blockIdx.x * 4 + (threadIdx.x >> 6);
    if (row >= n) return;
    const float* xr = X + (size_t)row * K;
    float acc = 0.0f;
#pragma unroll
    for (int k = 0; k < K; ++k) acc = fmaf(xr[k], Ws[k * FEAT + col], acc);
    C[(size_t)row * FEAT + col] = acc;
}

// One wave per edge: 64 lanes = 64 features. Per-edge scalars are
// wave-uniform (broadcast loads). Gather 256B contiguous, scatter atomic.
__global__ void scatter_kernel(const int* __restrict__ src, const int* __restrict__ dst,
                               const float* __restrict__ lin, const float* __restrict__ dinv,
                               float* __restrict__ out, int E) {
    long long t = (long long)blockIdx.x * 256 + threadIdx.x;
    int e = (int)(t >> 6);
    if (e >= E) return;
    int f = (int)(t & 63);
    int s = src[e], d = dst[e];
    float nrm = dinv[s] * dinv[d];
    atomicAdd(&out[(size_t)d * FEAT + f], lin[(size_t)s * FEAT + f] * nrm);
}

// out = agg + lin*dinv^2 + b  (optional relu); in-place safe (agg may == out).
__global__ void epilogue_kernel(const float* __restrict__ agg, const float* __restrict__ lin,
                                const float* __restrict__ dinv, const float* __restrict__ bias,
                                float* __restrict__ out, int n, int do_relu) {
    long long t = (long long)blockIdx.x * 256 + threadIdx.x;
    int i = (int)(t >> 6);
    if (i >= n) return;
    int f = (int)(t & 63);
    float di = dinv[i];
    float v = agg[(size_t)i * FEAT + f] + lin[(size_t)i * FEAT + f] * di * di + bias[f];
    if (do_relu) v = fmaxf(v, 0.0f);
    out[(size_t)i * FEAT + f] = v;
}

extern "C" void kernel_launch(void* const* d_in, const int* in_sizes, int n_in,
                              void* d_out, int out_size, void* d_ws, size_t ws_size,
                              hipStream_t stream) {
    const float* x    = (const float*)d_in[0];
    const int*   ei   = (const int*)d_in[1];
    const float* W1   = (const float*)d_in[2];
    const float* b1   = (const float*)d_in[3];
    const float* Wmu  = (const float*)d_in[4];
    const float* bmu  = (const float*)d_in[5];
    const float* Wls  = (const float*)d_in[6];
    const float* bls  = (const float*)d_in[7];

    const int N = in_sizes[0] / 128;       // 100000
    const int E = in_sizes[1] / 2;         // 1600000
    const int* src = ei;
    const int* dst = ei + E;

    float* dinv = (float*)d_ws;                  // N floats
    float* A    = dinv + N;                      // N*64 floats (h1, then lin_mu, then lin_ls)
    float* B    = A + (size_t)N * FEAT;          // N*64 floats (agg1 -> h)
    float* mu   = (float*)d_out;                 // N*64
    float* ls   = mu + (size_t)N * FEAT;         // N*64

    const int TB = 256;
    dim3 blk(TB);
    int grid_e   = (E + TB - 1) / TB;
    int grid_n   = (N + TB - 1) / TB;
    int grid_n4  = (N + 3) / 4;                  // gemm: 4 rows/block
    long long ef = (long long)E * FEAT;
    int grid_ef  = (int)((ef + TB - 1) / TB);
    long long nf = (long long)N * FEAT;
    int grid_nf  = (int)((nf + TB - 1) / TB);

    // --- degrees ---
    hipMemsetAsync(dinv, 0, (size_t)N * sizeof(float), stream);
    deg_count_kernel<<<grid_e, blk, 0, stream>>>(dst, dinv, E);
    dinv_kernel<<<grid_n, blk, 0, stream>>>(dinv, N);

    // --- layer 1: h = relu(agg(x@W1) + (x@W1)*dinv^2 + b1) ---
    gemm_kernel<128><<<grid_n4, blk, 0, stream>>>(x, W1, A, N);
    hipMemsetAsync(B, 0, (size_t)N * FEAT * sizeof(float), stream);
    scatter_kernel<<<grid_ef, blk, 0, stream>>>(src, dst, A, dinv, B, E);
    epilogue_kernel<<<grid_nf, blk, 0, stream>>>(B, A, dinv, b1, B, N, 1);

    // --- mu ---
    gemm_kernel<64><<<grid_n4, blk, 0, stream>>>(B, Wmu, A, N);
    hipMemsetAsync(mu, 0, (size_t)N * FEAT * sizeof(float), stream);
    scatter_kernel<<<grid_ef, blk, 0, stream>>>(src, dst, A, dinv, mu, E);
    epilogue_kernel<<<grid_nf, blk, 0, stream>>>(mu, A, dinv, bmu, mu, N, 0);

    // --- logstd ---
    gemm_kernel<64><<<grid_n4, blk, 0, stream>>>(B, Wls, A, N);
    hipMemsetAsync(ls, 0, (size_t)N * FEAT * sizeof(float), stream);
    scatter_kernel<<<grid_ef, blk, 0, stream>>>(src, dst, A, dinv, ls, E);
    epilogue_kernel<<<grid_nf, blk, 0, stream>>>(ls, A, dinv, bls, ls, N, 0);
}

// Round 2
// 523.411 us; speedup vs baseline: 2.7256x; 2.7256x over previous
//
#include <hip/hip_runtime.h>

// GCN encoder via CSR aggregation (no float atomics):
//   h    = relu(agg(x@W1) + b1)            agg(L)[i] = sum_e->i nrm*L[src] + L[i]*dinv[i]^2
//   Hagg = agg(h)
//   mu   = Hagg@Wmu + bmu ;  ls = Hagg@Wls + bls     (linearity: agg(h@W) == agg(h)@W)

static constexpr int FEAT = 64;
static constexpr int CHUNK = 2048;   // elements per scan block (256 thr x 8)

__global__ void deg_count_kernel(const int* __restrict__ dst, int* __restrict__ deg, int E) {
    int e = blockIdx.x * 256 + threadIdx.x;
    if (e < E) atomicAdd(&deg[dst[e]], 1);
}

__global__ void dinv_kernel(const int* __restrict__ deg, float* __restrict__ dinv, int n) {
    int i = blockIdx.x * 256 + threadIdx.x;
    if (i < n) dinv[i] = rsqrtf((float)deg[i] + 1.0f);
}

__global__ void chunk_sum_kernel(const int* __restrict__ deg, int* __restrict__ csum, int n) {
    __shared__ int s[256];
    int base = blockIdx.x * CHUNK;
    int t = 0;
    for (int j = threadIdx.x; j < CHUNK; j += 256) { int i = base + j; t += (i < n) ? deg[i] : 0; }
    s[threadIdx.x] = t; __syncthreads();
    for (int off = 128; off > 0; off >>= 1) {
        if (threadIdx.x < off) s[threadIdx.x] += s[threadIdx.x + off];
        __syncthreads();
    }
    if (threadIdx.x == 0) csum[blockIdx.x] = s[0];
}

__global__ void scan_chunk_kernel(int* __restrict__ csum, int nchunks,
                                  int* __restrict__ rowptr, int n, int E) {
    if (blockIdx.x == 0 && threadIdx.x == 0) {
        int acc = 0;
        for (int i = 0; i < nchunks; ++i) { int v = csum[i]; csum[i] = acc; acc += v; }
        rowptr[n] = E;
    }
}

__global__ void rowptr_kernel(const int* __restrict__ deg, const int* __restrict__ csum,
                              int* __restrict__ rowptr, int n) {
    __shared__ int s[256];
    int base = blockIdx.x * CHUNK;
    int tb = base + threadIdx.x * 8;
    int v[8]; int tsum = 0;
#pragma unroll
    for (int j = 0; j < 8; ++j) { int i = tb + j; v[j] = (i < n) ? deg[i] : 0; tsum += v[j]; }
    s[threadIdx.x] = tsum; __syncthreads();
    for (int off = 1; off < 256; off <<= 1) {            // inclusive Hillis-Steele
        int t = (threadIdx.x >= (unsigned)off) ? s[threadIdx.x - off] : 0;
        __syncthreads();
        s[threadIdx.x] += t;
        __syncthreads();
    }
    int excl = s[threadIdx.x] - tsum + csum[blockIdx.x];
#pragma unroll
    for (int j = 0; j < 8; ++j) { int i = tb + j; if (i < n) rowptr[i] = excl; excl += v[j]; }
}

__global__ void fill_kernel(const int* __restrict__ src, const int* __restrict__ dst,
                            const float* __restrict__ dinv, const int* __restrict__ rowptr,
                            int* __restrict__ cur, int* __restrict__ ssrc,
                            float* __restrict__ snrm, int E) {
    int e = blockIdx.x * 256 + threadIdx.x;
    if (e >= E) return;
    int s = src[e], d = dst[e];
    int pos = rowptr[d] + atomicAdd(&cur[d], 1);
    ssrc[pos] = s;
    snrm[pos] = dinv[s] * dinv[d];
}

// One wave per node; 64 lanes = 64 features. Sequential edge loop, unroll x4
// to keep 4 gathers in flight. All per-edge scalars are wave-uniform broadcasts.
__global__ void agg_kernel(const float* __restrict__ lin, const int* __restrict__ rowptr,
                           const int* __restrict__ ssrc, const float* __restrict__ snrm,
                           const float* __restrict__ dinv, const float* __restrict__ bias,
                           float* __restrict__ out, int n, int do_relu) {
    int node = blockIdx.x * 4 + (threadIdx.x >> 6);
    if (node >= n) return;
    int f = threadIdx.x & 63;
    int beg = rowptr[node], end = rowptr[node + 1];
    float di = dinv[node];
    float acc = lin[(size_t)node * FEAT + f] * di * di;   // self-loop message
    int p = beg;
    for (; p + 4 <= end; p += 4) {
        int   s0 = ssrc[p],  s1 = ssrc[p + 1],  s2 = ssrc[p + 2],  s3 = ssrc[p + 3];
        float n0 = snrm[p],  n1 = snrm[p + 1],  n2 = snrm[p + 2],  n3 = snrm[p + 3];
        float v0 = lin[(size_t)s0 * FEAT + f];
        float v1 = lin[(size_t)s1 * FEAT + f];
        float v2 = lin[(size_t)s2 * FEAT + f];
        float v3 = lin[(size_t)s3 * FEAT + f];
        acc = fmaf(v0, n0, acc); acc = fmaf(v1, n1, acc);
        acc = fmaf(v2, n2, acc); acc = fmaf(v3, n3, acc);
    }
    for (; p < end; ++p) acc = fmaf(lin[(size_t)ssrc[p] * FEAT + f], snrm[p], acc);
    if (bias) acc += bias[f];
    if (do_relu) acc = fmaxf(acc, 0.0f);
    out[(size_t)node * FEAT + f] = acc;
}

// C[n][64] = X[n][K] @ W[K][64]; 256 threads = 4 rows x 64 cols.
template<int K>
__global__ void gemm_kernel(const float* __restrict__ X, const float* __restrict__ W,
                            float* __restrict__ C, int n) {
    __shared__ float Ws[K * FEAT];
    for (int i = threadIdx.x; i < K * FEAT; i += 256) Ws[i] = W[i];
    __syncthreads();
    int col = threadIdx.x & 63;
    int row = blockIdx.x * 4 + (threadIdx.x >> 6);
    if (row >= n) return;
    const float* xr = X + (size_t)row * K;
    float acc = 0.0f;
#pragma unroll
    for (int k = 0; k < K; ++k) acc = fmaf(xr[k], Ws[k * FEAT + col], acc);
    C[(size_t)row * FEAT + col] = acc;
}

// mu = H@Wmu + bmu ; ls = H@Wls + bls. Reads H row fully before writing
// (wave-lockstep) so mu may alias H.
__global__ void gemm_dual_kernel(const float* __restrict__ H,
                                 const float* __restrict__ Wmu, const float* __restrict__ bmu,
                                 const float* __restrict__ Wls, const float* __restrict__ bls,
                                 float* __restrict__ mu, float* __restrict__ ls, int n) {
    __shared__ float Wm[64 * 64];
    __shared__ float Wl[64 * 64];
    for (int i = threadIdx.x; i < 64 * 64; i += 256) { Wm[i] = Wmu[i]; Wl[i] = Wls[i]; }
    __syncthreads();
    int col = threadIdx.x & 63;
    int row = blockIdx.x * 4 + (threadIdx.x >> 6);
    if (row >= n) return;
    const float* hr = H + (size_t)row * 64;
    float am = bmu[col], al = bls[col];
#pragma unroll
    for (int k = 0; k < 64; ++k) {
        float h = hr[k];
        am = fmaf(h, Wm[k * 64 + col], am);
        al = fmaf(h, Wl[k * 64 + col], al);
    }
    mu[(size_t)row * 64 + col] = am;
    ls[(size_t)row * 64 + col] = al;
}

extern "C" void kernel_launch(void* const* d_in, const int* in_sizes, int n_in,
                              void* d_out, int out_size, void* d_ws, size_t ws_size,
                              hipStream_t stream) {
    const float* x   = (const float*)d_in[0];
    const int*   ei  = (const int*)d_in[1];
    const float* W1  = (const float*)d_in[2];
    const float* b1  = (const float*)d_in[3];
    const float* Wmu = (const float*)d_in[4];
    const float* bmu = (const float*)d_in[5];
    const float* Wls = (const float*)d_in[6];
    const float* bls = (const float*)d_in[7];

    const int N = in_sizes[0] / 128;
    const int E = in_sizes[1] / 2;
    const int* src = ei;
    const int* dst = ei + E;

    const int nchunks = (N + CHUNK - 1) / CHUNK;

    // workspace layout (all 4-byte elements)
    int*   deg    = (int*)d_ws;                 // N
    int*   cur    = deg + N;                    // N
    float* dinv   = (float*)(cur + N);          // N
    int*   rowptr = (int*)(dinv + N);           // N+1
    int*   csum   = rowptr + N + 1;             // nchunks
    int*   ssrc   = csum + ((nchunks + 63) & ~63); // E
    float* snrm   = (float*)(ssrc + E);         // E
    float* A      = snrm + E;                   // N*64  (x@W1)

    float* mu_slot = (float*)d_out;             // N*64: Hagg then mu
    float* ls_slot = mu_slot + (size_t)N * FEAT;// N*64: h    then ls

    const int TB = 256;
    int grid_e  = (E + TB - 1) / TB;
    int grid_n  = (N + TB - 1) / TB;
    int grid_n4 = (N + 3) / 4;

    // ---- CSR build ----
    hipMemsetAsync(deg, 0, (size_t)2 * N * sizeof(int), stream);  // deg + cur
    deg_count_kernel<<<grid_e, TB, 0, stream>>>(dst, deg, E);
    dinv_kernel<<<grid_n, TB, 0, stream>>>(deg, dinv, N);
    chunk_sum_kernel<<<nchunks, TB, 0, stream>>>(deg, csum, N);
    scan_chunk_kernel<<<1, TB, 0, stream>>>(csum, nchunks, rowptr, N, E);
    rowptr_kernel<<<nchunks, TB, 0, stream>>>(deg, csum, rowptr, N);
    fill_kernel<<<grid_e, TB, 0, stream>>>(src, dst, dinv, rowptr, cur, ssrc, snrm, E);

    // ---- layer 1: h = relu(agg(x@W1) + b1) ----
    gemm_kernel<128><<<grid_n4, TB, 0, stream>>>(x, W1, A, N);
    agg_kernel<<<grid_n4, TB, 0, stream>>>(A, rowptr, ssrc, snrm, dinv, b1, ls_slot, N, 1);

    // ---- shared aggregation: Hagg = agg(h) ----
    agg_kernel<<<grid_n4, TB, 0, stream>>>(ls_slot, rowptr, ssrc, snrm, dinv, nullptr, mu_slot, N, 0);

    // ---- heads: mu = Hagg@Wmu + bmu (in-place), ls = Hagg@Wls + bls ----
    gemm_dual_kernel<<<grid_n4, TB, 0, stream>>>(mu_slot, Wmu, bmu, Wls, bls, mu_slot, ls_slot, N);
}

// Round 3
// 395.804 us; speedup vs baseline: 3.6043x; 1.3224x over previous
//
#include <hip/hip_runtime.h>

// GCN encoder, CSR aggregation with separable norm + bf16 gather tables.
//   dinv[i] = rsqrt(deg_in[i]+1)
//   T1 = bf16( dinv * (x@W1) )                       [gemm1, fused scale+quant]
//   T2 = bf16( dinv * relu( dinv*aggsum(T1) + b1 ) ) [agg<0>]
//   Hagg = dinv * aggsum(T2)                         [agg<1>, fp32]
//   mu = Hagg@Wmu+bmu ; ls = Hagg@Wls+bls            [fused dual gemm]
// where aggsum(T)[d] = sum_{s->d} T[s] + T[d]  (self-loop included).

using uint = unsigned int;

static constexpr int FEAT = 64;
static constexpr int CHUNK = 2048;

static __device__ __forceinline__ ushort f2bf(float f) {
    uint u = __float_as_uint(f);
    u += 0x7FFFu + ((u >> 16) & 1u);
    return (ushort)(u >> 16);
}
static __device__ __forceinline__ float bf2f(ushort b) {
    return __uint_as_float(((uint)b) << 16);
}

__global__ void deg_count_kernel(const int* __restrict__ dst, int* __restrict__ deg, int E) {
    int e = blockIdx.x * 256 + threadIdx.x;
    if (e < E) atomicAdd(&deg[dst[e]], 1);
}

__global__ void dinv_kernel(const int* __restrict__ deg, float* __restrict__ dinv, int n) {
    int i = blockIdx.x * 256 + threadIdx.x;
    if (i < n) dinv[i] = rsqrtf((float)deg[i] + 1.0f);
}

__global__ void chunk_sum_kernel(const int* __restrict__ deg, int* __restrict__ csum, int n) {
    __shared__ int s[256];
    int base = blockIdx.x * CHUNK;
    int t = 0;
    for (int j = threadIdx.x; j < CHUNK; j += 256) { int i = base + j; t += (i < n) ? deg[i] : 0; }
    s[threadIdx.x] = t; __syncthreads();
    for (int off = 128; off > 0; off >>= 1) {
        if (threadIdx.x < off) s[threadIdx.x] += s[threadIdx.x + off];
        __syncthreads();
    }
    if (threadIdx.x == 0) csum[blockIdx.x] = s[0];
}

__global__ void scan_chunk_kernel(int* __restrict__ csum, int nchunks,
                                  int* __restrict__ rowptr, int n, int E) {
    if (blockIdx.x == 0 && threadIdx.x == 0) {
        int acc = 0;
        for (int i = 0; i < nchunks; ++i) { int v = csum[i]; csum[i] = acc; acc += v; }
        rowptr[n] = E;
    }
}

__global__ void rowptr_kernel(const int* __restrict__ deg, const int* __restrict__ csum,
                              int* __restrict__ rowptr, int n) {
    __shared__ int s[256];
    int base = blockIdx.x * CHUNK;
    int tb = base + threadIdx.x * 8;
    int v[8]; int tsum = 0;
#pragma unroll
    for (int j = 0; j < 8; ++j) { int i = tb + j; v[j] = (i < n) ? deg[i] : 0; tsum += v[j]; }
    s[threadIdx.x] = tsum; __syncthreads();
    for (int off = 1; off < 256; off <<= 1) {
        int t = (threadIdx.x >= (unsigned)off) ? s[threadIdx.x - off] : 0;
        __syncthreads();
        s[threadIdx.x] += t;
        __syncthreads();
    }
    int excl = s[threadIdx.x] - tsum + csum[blockIdx.x];
#pragma unroll
    for (int j = 0; j < 8; ++j) { int i = tb + j; if (i < n) rowptr[i] = excl; excl += v[j]; }
}

__global__ void fill_kernel(const int* __restrict__ src, const int* __restrict__ dst,
                            const int* __restrict__ rowptr, int* __restrict__ cur,
                            int* __restrict__ ssrc, int E) {
    int e = blockIdx.x * 256 + threadIdx.x;
    if (e >= E) return;
    int s = src[e], d = dst[e];
    int pos = rowptr[d] + atomicAdd(&cur[d], 1);
    ssrc[pos] = s;
}

// T1[row][c] = bf16(dinv[row] * (X@W1)[row][c]).  64-row block tile; W and X^T
// staged in LDS (X transposed -> conflict-free reads); thread computes 4 rows x 4 cols.
__global__ __launch_bounds__(256) void gemm1_kernel(const float* __restrict__ X,
                                                    const float* __restrict__ W,
                                                    const float* __restrict__ dinv,
                                                    ushort* __restrict__ T1, int n) {
    __shared__ float Ws[128 * 64];   // 32 KB
    __shared__ float Xs[128 * 64];   // 32 KB, [k][row]
    int tid = threadIdx.x;
    int rowbase = blockIdx.x * 64;
    {
        const float4* Wv = (const float4*)W;
        float4* Wsv = (float4*)Ws;
#pragma unroll
        for (int j = 0; j < 8; ++j) Wsv[tid + 256 * j] = Wv[tid + 256 * j];
    }
    {
        int k4 = (tid & 31) * 4;
        int r0 = tid >> 5;
#pragma unroll
        for (int j = 0; j < 8; ++j) {
            int r = r0 + 8 * j;
            int row = rowbase + r;
            float4 v = make_float4(0.f, 0.f, 0.f, 0.f);
            if (row < n) v = *(const float4*)(X + (size_t)row * 128 + k4);
            Xs[(k4 + 0) * 64 + r] = v.x;
            Xs[(k4 + 1) * 64 + r] = v.y;
            Xs[(k4 + 2) * 64 + r] = v.z;
            Xs[(k4 + 3) * 64 + r] = v.w;
        }
    }
    __syncthreads();
    int lane = tid & 63;
    int wave = tid >> 6;
    int colq = (lane & 15) * 4;
    int rloc = wave * 16 + (lane >> 4) * 4;
    float acc[4][4];
#pragma unroll
    for (int i = 0; i < 4; ++i)
#pragma unroll
        for (int j = 0; j < 4; ++j) acc[i][j] = 0.f;
#pragma unroll 4
    for (int k = 0; k < 128; ++k) {
        float4 w = *(const float4*)&Ws[k * 64 + colq];
        float x0 = Xs[k * 64 + rloc + 0];
        float x1 = Xs[k * 64 + rloc + 1];
        float x2 = Xs[k * 64 + rloc + 2];
        float x3 = Xs[k * 64 + rloc + 3];
        acc[0][0] = fmaf(x0, w.x, acc[0][0]); acc[0][1] = fmaf(x0, w.y, acc[0][1]);
        acc[0][2] = fmaf(x0, w.z, acc[0][2]); acc[0][3] = fmaf(x0, w.w, acc[0][3]);
        acc[1][0] = fmaf(x1, w.x, acc[1][0]); acc[1][1] = fmaf(x1, w.y, acc[1][1]);
        acc[1][2] = fmaf(x1, w.z, acc[1][2]); acc[1][3] = fmaf(x1, w.w, acc[1][3]);
        acc[2][0] = fmaf(x2, w.x, acc[2][0]); acc[2][1] = fmaf(x2, w.y, acc[2][1]);
        acc[2][2] = fmaf(x2, w.z, acc[2][2]); acc[2][3] = fmaf(x2, w.w, acc[2][3]);
        acc[3][0] = fmaf(x3, w.x, acc[3][0]); acc[3][1] = fmaf(x3, w.y, acc[3][1]);
        acc[3][2] = fmaf(x3, w.z, acc[3][2]); acc[3][3] = fmaf(x3, w.w, acc[3][3]);
    }
#pragma unroll
    for (int i = 0; i < 4; ++i) {
        int row = rowbase + rloc + i;
        if (row < n) {
            float di = dinv[row];
            ushort4 t;
            t.x = f2bf(acc[i][0] * di);
            t.y = f2bf(acc[i][1] * di);
            t.z = f2bf(acc[i][2] * di);
            t.w = f2bf(acc[i][3] * di);
            *(ushort4*)(T1 + (size_t)row * FEAT + colq) = t;
        }
    }
}

// One wave per node; 64 lanes = 64 feats. Gathers 128B bf16 rows, fp32 accum.
// MODE 0: Tout = bf16(dinv*relu(dinv*sum + bias)); MODE 1: Fout = dinv*sum.
template<int MODE>
__global__ __launch_bounds__(256) void agg_kernel(const ushort* __restrict__ T,
                                                  const int* __restrict__ rowptr,
                                                  const int* __restrict__ ssrc,
                                                  const float* __restrict__ dinv,
                                                  const float* __restrict__ bias,
                                                  ushort* __restrict__ Tout,
                                                  float* __restrict__ Fout, int n) {
    int node = blockIdx.x * 4 + (threadIdx.x >> 6);
    if (node >= n) return;
    int f = threadIdx.x & 63;
    int beg = rowptr[node], end = rowptr[node + 1];
    float di = dinv[node];
    float acc = bf2f(T[(size_t)node * FEAT + f]);   // self-loop term
    int p = beg;
    for (; p + 4 <= end; p += 4) {
        int s0 = ssrc[p], s1 = ssrc[p + 1], s2 = ssrc[p + 2], s3 = ssrc[p + 3];
        float v0 = bf2f(T[(size_t)s0 * FEAT + f]);
        float v1 = bf2f(T[(size_t)s1 * FEAT + f]);
        float v2 = bf2f(T[(size_t)s2 * FEAT + f]);
        float v3 = bf2f(T[(size_t)s3 * FEAT + f]);
        acc += (v0 + v1) + (v2 + v3);
    }
    for (; p < end; ++p) acc += bf2f(T[(size_t)ssrc[p] * FEAT + f]);
    if (MODE == 0) {
        float h = fmaf(di, acc, bias[f]);
        h = fmaxf(h, 0.0f);
        Tout[(size_t)node * FEAT + f] = f2bf(h * di);
    } else {
        Fout[(size_t)node * FEAT + f] = di * acc;
    }
}

// mu = H@Wmu+bmu, ls = H@Wls+bls. 64-row tile, both weights + H^T in LDS (48KB).
// In-place safe for mu==H (tile staged to LDS before any write; blocks only touch own rows).
__global__ __launch_bounds__(256) void gemm_dual_kernel(const float* __restrict__ H,
                                                        const float* __restrict__ Wmu,
                                                        const float* __restrict__ bmu,
                                                        const float* __restrict__ Wls,
                                                        const float* __restrict__ bls,
                                                        float* __restrict__ mu,
                                                        float* __restrict__ ls, int n) {
    __shared__ float Wm[64 * 64];    // 16 KB
    __shared__ float Wl[64 * 64];    // 16 KB
    __shared__ float Xs[64 * 64];    // 16 KB, [k][row]
    int tid = threadIdx.x;
    int rowbase = blockIdx.x * 64;
    {
        const float4* a = (const float4*)Wmu;
        const float4* b = (const float4*)Wls;
        float4* as = (float4*)Wm;
        float4* bs = (float4*)Wl;
#pragma unroll
        for (int j = 0; j < 4; ++j) { as[tid + 256 * j] = a[tid + 256 * j]; bs[tid + 256 * j] = b[tid + 256 * j]; }
    }
    {
        int k4 = (tid & 15) * 4;
        int r0 = tid >> 4;
#pragma unroll
        for (int j = 0; j < 4; ++j) {
            int r = r0 + 16 * j;
            int row = rowbase + r;
            float4 v = make_float4(0.f, 0.f, 0.f, 0.f);
            if (row < n) v = *(const float4*)(H + (size_t)row * 64 + k4);
            Xs[(k4 + 0) * 64 + r] = v.x;
            Xs[(k4 + 1) * 64 + r] = v.y;
            Xs[(k4 + 2) * 64 + r] = v.z;
            Xs[(k4 + 3) * 64 + r] = v.w;
        }
    }
    __syncthreads();
    int lane = tid & 63;
    int wave = tid >> 6;
    int colq = (lane & 15) * 4;
    int rloc = wave * 16 + (lane >> 4) * 4;
    float am[4][4], al[4][4];
#pragma unroll
    for (int i = 0; i < 4; ++i)
#pragma unroll
        for (int j = 0; j < 4; ++j) { am[i][j] = 0.f; al[i][j] = 0.f; }
#pragma unroll 4
    for (int k = 0; k < 64; ++k) {
        float4 wm = *(const float4*)&Wm[k * 64 + colq];
        float4 wl = *(const float4*)&Wl[k * 64 + colq];
        float x0 = Xs[k * 64 + rloc + 0];
        float x1 = Xs[k * 64 + rloc + 1];
        float x2 = Xs[k * 64 + rloc + 2];
        float x3 = Xs[k * 64 + rloc + 3];
        am[0][0] = fmaf(x0, wm.x, am[0][0]); am[0][1] = fmaf(x0, wm.y, am[0][1]);
        am[0][2] = fmaf(x0, wm.z, am[0][2]); am[0][3] = fmaf(x0, wm.w, am[0][3]);
        am[1][0] = fmaf(x1, wm.x, am[1][0]); am[1][1] = fmaf(x1, wm.y, am[1][1]);
        am[1][2] = fmaf(x1, wm.z, am[1][2]); am[1][3] = fmaf(x1, wm.w, am[1][3]);
        am[2][0] = fmaf(x2, wm.x, am[2][0]); am[2][1] = fmaf(x2, wm.y, am[2][1]);
        am[2][2] = fmaf(x2, wm.z, am[2][2]); am[2][3] = fmaf(x2, wm.w, am[2][3]);
        am[3][0] = fmaf(x3, wm.x, am[3][0]); am[3][1] = fmaf(x3, wm.y, am[3][1]);
        am[3][2] = fmaf(x3, wm.z, am[3][2]); am[3][3] = fmaf(x3, wm.w, am[3][3]);
        al[0][0] = fmaf(x0, wl.x, al[0][0]); al[0][1] = fmaf(x0, wl.y, al[0][1]);
        al[0][2] = fmaf(x0, wl.z, al[0][2]); al[0][3] = fmaf(x0, wl.w, al[0][3]);
        al[1][0] = fmaf(x1, wl.x, al[1][0]); al[1][1] = fmaf(x1, wl.y, al[1][1]);
        al[1][2] = fmaf(x1, wl.z, al[1][2]); al[1][3] = fmaf(x1, wl.w, al[1][3]);
        al[2][0] = fmaf(x2, wl.x, al[2][0]); al[2][1] = fmaf(x2, wl.y, al[2][1]);
        al[2][2] = fmaf(x2, wl.z, al[2][2]); al[2][3] = fmaf(x2, wl.w, al[2][3]);
        al[3][0] = fmaf(x3, wl.x, al[3][0]); al[3][1] = fmaf(x3, wl.y, al[3][1]);
        al[3][2] = fmaf(x3, wl.z, al[3][2]); al[3][3] = fmaf(x3, wl.w, al[3][3]);
    }
    float4 bm = *(const float4*)&bmu[colq];
    float4 bl = *(const float4*)&bls[colq];
#pragma unroll
    for (int i = 0; i < 4; ++i) {
        int row = rowbase + rloc + i;
        if (row < n) {
            *(float4*)(mu + (size_t)row * 64 + colq) =
                make_float4(am[i][0] + bm.x, am[i][1] + bm.y, am[i][2] + bm.z, am[i][3] + bm.w);
            *(float4*)(ls + (size_t)row * 64 + colq) =
                make_float4(al[i][0] + bl.x, al[i][1] + bl.y, al[i][2] + bl.z, al[i][3] + bl.w);
        }
    }
}

extern "C" void kernel_launch(void* const* d_in, const int* in_sizes, int n_in,
                              void* d_out, int out_size, void* d_ws, size_t ws_size,
                              hipStream_t stream) {
    const float* x   = (const float*)d_in[0];
    const int*   ei  = (const int*)d_in[1];
    const float* W1  = (const float*)d_in[2];
    const float* b1  = (const float*)d_in[3];
    const float* Wmu = (const float*)d_in[4];
    const float* bmu = (const float*)d_in[5];
    const float* Wls = (const float*)d_in[6];
    const float* bls = (const float*)d_in[7];

    const int N = in_sizes[0] / 128;
    const int E = in_sizes[1] / 2;
    const int* src = ei;
    const int* dst = ei + E;

    const int nchunks = (N + CHUNK - 1) / CHUNK;

    int*    deg    = (int*)d_ws;                    // N
    int*    cur    = deg + N;                       // N
    float*  dinv   = (float*)(cur + N);             // N
    int*    rowptr = (int*)(dinv + N);              // N+1
    int*    csum   = rowptr + N + 1;                // nchunks (padded)
    int*    ssrc   = csum + ((nchunks + 63) & ~63); // E
    ushort* T1     = (ushort*)(ssrc + E);           // N*64 bf16
    ushort* T2     = T1 + (size_t)N * FEAT;         // N*64 bf16

    float* mu_slot = (float*)d_out;                 // N*64: Hagg then mu (in-place)
    float* ls_slot = mu_slot + (size_t)N * FEAT;    // N*64: ls

    const int TB = 256;
    int grid_e  = (E + TB - 1) / TB;
    int grid_n  = (N + TB - 1) / TB;
    int grid_n4 = (N + 3) / 4;
    int grid_g  = (N + 63) / 64;

    // ---- CSR build (separable norm: payload is src index only) ----
    hipMemsetAsync(deg, 0, (size_t)2 * N * sizeof(int), stream);
    deg_count_kernel<<<grid_e, TB, 0, stream>>>(dst, deg, E);
    dinv_kernel<<<grid_n, TB, 0, stream>>>(deg, dinv, N);
    chunk_sum_kernel<<<nchunks, TB, 0, stream>>>(deg, csum, N);
    scan_chunk_kernel<<<1, TB, 0, stream>>>(csum, nchunks, rowptr, N, E);
    rowptr_kernel<<<nchunks, TB, 0, stream>>>(deg, csum, rowptr, N);
    fill_kernel<<<grid_e, TB, 0, stream>>>(src, dst, rowptr, cur, ssrc, E);

    // ---- T1 = bf16(dinv * (x@W1)) ----
    gemm1_kernel<<<grid_g, TB, 0, stream>>>(x, W1, dinv, T1, N);

    // ---- T2 = bf16(dinv * relu(dinv*aggsum(T1) + b1)) ----
    agg_kernel<0><<<grid_n4, TB, 0, stream>>>(T1, rowptr, ssrc, dinv, b1, T2, nullptr, N);

    // ---- Hagg = dinv * aggsum(T2) ----
    agg_kernel<1><<<grid_n4, TB, 0, stream>>>(T2, rowptr, ssrc, dinv, nullptr, nullptr, mu_slot, N);

    // ---- heads ----
    gemm_dual_kernel<<<grid_g, TB, 0, stream>>>(mu_slot, Wmu, bmu, Wls, bls, mu_slot, ls_slot, N);
}